// Round 1
// baseline (100.503 us; speedup 1.0000x reference)
//
#include <hip/hip_runtime.h>

#define GX 200
#define GY 200
#define GZ 16
#define NVOX (GX*GY*GZ)
#define NFEAT 8

#define NTX 50
#define NTY 50
#define NTILES (NTX*NTY)      // 2500 xy-tiles of 4x4 voxels
#define NSLAB 4               // z split into 4 slabs of 4 voxels
#define NBIN (NTILES*NSLAB)   // 10000 bins
#define CAP 160               // per-bin capacity (avg ~25)

// ws layout (ints):
//   [0, NBIN)                     counts
//   [NBIN, NBIN + NBIN*CAP*2)     buckets (int2: {gauss id, packed lane-mask})
//   records: 5 float4 per gaussian
#define WS_COUNTS 0
#define WS_BUCKETS NBIN
#define WS_RECORDS (NBIN + NBIN*CAP*2)   // 3,210,000 ints -> 16B aligned

// record (A' = inverse covariance with -0.5 / off-diag 2x pre-folded):
//   q0=(-.5A00, -A01, -A02, -.5A11)  q1=(-A12, -.5A22, opac, mx)
//   q2=(my,mz,f0,f1)  q3=(f2,f3,f4,f5)  q4=(f6,f7,0,0)

typedef float f32x4 __attribute__((ext_vector_type(4)));

__global__ __launch_bounds__(256) void prep_fill_kernel(
    const float* __restrict__ means, const float* __restrict__ opac,
    const float* __restrict__ cov, const float* __restrict__ feat,
    int* __restrict__ ws, float4* __restrict__ recs, int G)
{
    const int i = blockIdx.x*256 + threadIdx.x;
    const int g = i >> 4, s = i & 15;
    if (g >= G) return;

    const float lox = -40.f, loy = -40.f, loz = -1.f;
    const float hix =  40.f, hiy =  40.f, hiz =  5.4f;
    const float mx = means[g*3+0], my = means[g*3+1], mz = means[g*3+2];
    const float c00 = cov[g*9+0], c01 = cov[g*9+1], c02 = cov[g*9+2];
    const float c10 = cov[g*9+3], c11 = cov[g*9+4], c12 = cov[g*9+5];
    const float c20 = cov[g*9+6], c21 = cov[g*9+7], c22 = cov[g*9+8];

    const float sx = sqrtf(c00), sy = sqrtf(c11), sz = sqrtf(c22);
    const float blx = mx - 3.0f*sx, bly = my - 3.0f*sy, blz = mz - 3.0f*sz;
    const float bhx = mx + 3.0f*sx, bhy = my + 3.0f*sy, bhz = mz + 3.0f*sz;
    const bool valid = (bhx > lox) & (bhy > loy) & (bhz > loz)
                     & (blx < hix) & (bly < hiy) & (blz < hiz);
    if (!valid) return;

    float blxc = fminf(fmaxf(blx, lox), hix);
    float blyc = fminf(fmaxf(bly, loy), hiy);
    float blzc = fminf(fmaxf(blz, loz), hiz);
    float bhxc = fminf(fmaxf(bhx, lox), hix);
    float bhyc = fminf(fmaxf(bhy, loy), hiy);
    float bhzc = fminf(fmaxf(bhz, loz), hiz);
    int ilox = (int)((blxc - lox) / 0.4f);
    int iloy = (int)((blyc - loy) / 0.4f);
    int iloz = (int)((blzc - loz) / 0.4f);
    int ihix = (int)((bhxc - lox) / 0.4f);
    int ihiy = (int)((bhyc - loy) / 0.4f);
    int ihiz = (int)((bhzc - loz) / 0.4f);
    ilox = min(ilox, GX-1); iloy = min(iloy, GY-1); iloz = min(iloz, GZ-1);
    ihix = min(ihix, GX-1); ihiy = min(ihiy, GY-1); ihiz = min(ihiz, GZ-1);

    // record write: lanes s=0..4 each store one float4 (contiguous 80 B)
    if (s < 5) {
        const float m00 = c11*c22 - c12*c21;
        const float m01 = c10*c22 - c12*c20;
        const float m02 = c10*c21 - c11*c20;
        const float det = c00*m00 - c01*m01 + c02*m02;
        const float ni = -1.0f / det;    // -idet  (off-diag: -A_ij, folds 2x * -0.5)
        const float hd = 0.5f * ni;      // -0.5*idet (diagonal terms)
        float4 q;
        if (s == 0) {
            q.x = m00 * hd;                  // -0.5*A00
            q.y = (c02*c21 - c01*c22) * ni;  // -A01
            q.z = (c01*c12 - c02*c11) * ni;  // -A02
            q.w = (c00*c22 - c02*c20) * hd;  // -0.5*A11
        } else if (s == 1) {
            q.x = (c02*c10 - c00*c12) * ni;  // -A12
            q.y = (c00*c11 - c01*c10) * hd;  // -0.5*A22
            q.z = opac[g];
            q.w = mx;
        } else if (s == 2) {
            q.x = my;
            q.y = mz;
            q.z = feat[g*8+0];
            q.w = feat[g*8+1];
        } else if (s == 3) {
            q.x = feat[g*8+2]; q.y = feat[g*8+3]; q.z = feat[g*8+4]; q.w = feat[g*8+5];
        } else {
            q.x = feat[g*8+6]; q.y = feat[g*8+7]; q.z = 0.f; q.w = 0.f;
        }
        recs[(size_t)g*5 + s] = q;
    }

    // binning: slot (s>>2, s&3) covers xy-tile (txlo + s>>2, tylo + s&3)
    const int txlo = ilox >> 2, txhi = ihix >> 2;
    const int tylo = iloy >> 2, tyhi = ihiy >> 2;
    const int tx = txlo + (s >> 2);
    const int ty = tylo + (s & 3);
    if (tx <= txhi && ty <= tyhi) {
        // per-(gaussian,tile) xy lane mask: bit (lx*4+ly) set iff voxel in box
        const int lxlo = max(ilox - tx*4, 0), lxhi = min(ihix - tx*4, 3);
        const int lylo = max(iloy - ty*4, 0), lyhi = min(ihiy - ty*4, 3);
        const int xm = ((1 << (lxhi+1)) - 1) & ~((1 << lxlo) - 1);   // 4 bits
        const int ym = ((1 << (lyhi+1)) - 1) & ~((1 << lylo) - 1);   // 4 bits
        const int spread = (xm & 1) + (xm & 2)*8 + (xm & 4)*64 + (xm & 8)*512;
        const int xymask = ym * spread;                               // 16 bits

        const int slo = iloz >> 2, shi = ihiz >> 2;
        const int base = (tx*NTY + ty)*NSLAB;
        int2* __restrict__ bkt = (int2*)(ws + WS_BUCKETS);
        for (int sl = slo; sl <= shi; ++sl) {
            const int lzlo = max(iloz - sl*4, 0), lzhi = min(ihiz - sl*4, 3);
            const int zm = ((1 << (lzhi+1)) - 1) & ~((1 << lzlo) - 1);
            const int pos = atomicAdd(&ws[WS_COUNTS + base + sl], 1);
            if (pos < CAP) {
                int2 e; e.x = g; e.y = xymask | (zm << 16);
                bkt[(size_t)(base + sl)*CAP + pos] = e;
            }
        }
    }
}

__global__ __launch_bounds__(256) void gather_kernel(
    const int* __restrict__ ws, const float4* __restrict__ recs,
    float* __restrict__ dens_out, float* __restrict__ feat_out)
{
    const int tile = blockIdx.x;
    const int tx = tile / NTY, ty = tile % NTY;
    const int t = threadIdx.x;
    const int w = t >> 6, l = t & 63;          // wave w owns z-slab [4w, 4w+4)
    const int lx = l >> 4, ly = (l >> 2) & 3, lz = l & 3;
    const int ix = tx*4 + lx, iy = ty*4 + ly, iz = w*4 + lz;
    const int sh_xy = lx*4 + ly;               // bit index in xymask
    const int sh_z  = 16 + lz;                 // bit index of zmask

    const float cx = ((float)ix + 0.5f) * 0.4f + (-40.f);
    const float cy = ((float)iy + 0.5f) * 0.4f + (-40.f);
    const float cz = ((float)iz + 0.5f) * 0.4f + (-1.f);

    const int bin = tile*NSLAB + w;
    const int n = min(ws[WS_COUNTS + bin], CAP);
    const int2* __restrict__ bkt = (const int2*)(ws + WS_BUCKETS) + (size_t)bin*CAP;

    float den = 0.f;
    float a0=0.f,a1=0.f,a2=0.f,a3=0.f,a4=0.f,a5=0.f,a6=0.f,a7=0.f;

    if (n > 0) {
        // software pipeline: entry j in {e,q*}; entry j+1 in {en, prefetched next iter};
        // entry j+2 address prefetched into e2. All record loads are wave-uniform.
        int2 e  = bkt[0];
        int2 en = bkt[min(1, n-1)];
        {
            const int g0 = __builtin_amdgcn_readfirstlane(e.x);
            const float4* __restrict__ r = recs + (size_t)g0 * 5;
            float4 q0 = r[0], q1 = r[1], q2 = r[2], q3 = r[3];
            float2 q4 = *(const float2*)(r + 4);

            #pragma unroll 2
            for (int j = 0; j < n; ++j) {
                const int msk = e.y;

                // issue next entry's record loads BEFORE this entry's compute
                const int gn = __builtin_amdgcn_readfirstlane(en.x);
                const float4* __restrict__ rn = recs + (size_t)gn * 5;
                const float4 t0 = rn[0], t1 = rn[1], t2 = rn[2], t3 = rn[3];
                const float2 t4 = *(const float2*)(rn + 4);
                const int2 e2 = bkt[min(j + 2, n - 1)];

                // 2-shift box test from precomputed lane masks
                const bool in = ((msk >> sh_xy) & (msk >> sh_z) & 1) != 0;

                const float X = cx - q1.w, Y = cy - q2.x, Z = cz - q2.y;
                // exponent directly: coefficients pre-folded with -0.5 / 2x
                const float m = q0.x*(X*X) + q0.w*(Y*Y) + q1.y*(Z*Z)
                              + q0.y*(X*Y) + q0.z*(X*Z) + q1.x*(Y*Z);
                float wgt = q1.z * __expf(m);
                wgt = in ? wgt : 0.f;
                den += wgt;
                a0 += wgt*q2.z; a1 += wgt*q2.w;   // f0,f1
                a2 += wgt*q3.x; a3 += wgt*q3.y;   // f2,f3
                a4 += wgt*q3.z; a5 += wgt*q3.w;   // f4,f5
                a6 += wgt*q4.x; a7 += wgt*q4.y;   // f6,f7

                // rotate pipeline (renamed away under unroll 2)
                e = en; en = e2;
                q0 = t0; q1 = t1; q2 = t2; q3 = t3; q4 = t4;
            }
        }
    }

    const int flat = (ix*GY + iy)*GZ + iz;
    const float dc  = fmaxf(den, 1e-6f);
    const float inv = 1.0f / dc;               // one divide, 8 muls (was 8 divides)

    __builtin_nontemporal_store(den, dens_out + flat);
    f32x4 fa = { a0*inv, a1*inv, a2*inv, a3*inv };
    f32x4 fb = { a4*inv, a5*inv, a6*inv, a7*inv };
    f32x4* fp = (f32x4*)(feat_out + (size_t)flat * NFEAT);
    __builtin_nontemporal_store(fa, fp);
    __builtin_nontemporal_store(fb, fp + 1);
}

extern "C" void kernel_launch(void* const* d_in, const int* in_sizes, int n_in,
                              void* d_out, int out_size, void* d_ws, size_t ws_size,
                              hipStream_t stream) {
    const float* means = (const float*)d_in[0];
    const float* opac  = (const float*)d_in[1];
    const float* cov   = (const float*)d_in[2];
    const float* feat  = (const float*)d_in[3];
    const int G = in_sizes[0] / 3;

    float* dens_out = (float*)d_out;
    float* feat_out = dens_out + NVOX;
    int* ws = (int*)d_ws;
    float4* recs = (float4*)((char*)d_ws + (size_t)WS_RECORDS * sizeof(int));

    hipMemsetAsync(ws, 0, NBIN * sizeof(int), stream);
    prep_fill_kernel<<<(G*16 + 255)/256, 256, 0, stream>>>(means, opac, cov, feat,
                                                           ws, recs, G);
    gather_kernel<<<NTILES, 256, 0, stream>>>(ws, recs, dens_out, feat_out);
}